// Round 7
// baseline (1181.902 us; speedup 1.0000x reference)
//
#include <hip/hip_runtime.h>
#include <math.h>

#define Bsz 8
#define Dd  128
#define Tt  4096
#define Kk  1024
#define NQ  8
#define BT  (Bsz*Tt)        // 32768 points
#define PW  16              // points per block (shared by 4 waves)
#define CPL 4               // codes per lane (64 lanes * 4 = 256 codes/wave)

typedef float v2f __attribute__((ext_vector_type(2)));

// ---------------------------------------------------------------------------
// init: transpose x (B,D,T) -> resid (B,T,D)
// ---------------------------------------------------------------------------
__global__ void k_init(const float* __restrict__ x,
                       float* __restrict__ resid) {
    __shared__ float tile[32][33];
    int b  = blockIdx.z;
    int t0 = blockIdx.x * 32, d0 = blockIdx.y * 32;
    int tx = threadIdx.x, ty = threadIdx.y;   // 32 x 8
    #pragma unroll
    for (int k = 0; k < 4; k++) {
        int d = d0 + ty + k * 8;
        tile[ty + k * 8][tx] = x[((size_t)(b * Dd + d)) * Tt + t0 + tx];
    }
    __syncthreads();
    #pragma unroll
    for (int k = 0; k < 4; k++) {
        int t = t0 + ty + k * 8;
        resid[((size_t)(b * Tt + t)) * Dd + d0 + tx] = tile[tx][ty + k * 8];
    }
}

// ---------------------------------------------------------------------------
// cbT[q][d][k] = cb[q][k][d]  (once; reused by all stages)
// ---------------------------------------------------------------------------
__global__ void k_cbT(const float* __restrict__ cb, float* __restrict__ cbT) {
    __shared__ float tile[32][33];
    int q  = blockIdx.z;
    int k0 = blockIdx.x * 32, d0 = blockIdx.y * 32;
    int tx = threadIdx.x, ty = threadIdx.y;   // 32 x 8
    const float* src = cb  + (size_t)q * Kk * Dd;
    float*       dst = cbT + (size_t)q * Dd * Kk;
    #pragma unroll
    for (int r = 0; r < 4; r++) {
        int k = k0 + ty + r * 8;
        tile[ty + r * 8][tx] = src[(size_t)k * Dd + d0 + tx];
    }
    __syncthreads();
    #pragma unroll
    for (int r = 0; r < 4; r++) {
        int d = d0 + ty + r * 8;
        dst[(size_t)d * Kk + k0 + tx] = tile[tx][ty + r * 8];
    }
}

// ---------------------------------------------------------------------------
// c2[q][k] = sum_d cb[q][k][d]^2 ; zero commit accumulators
// ---------------------------------------------------------------------------
__global__ void k_c2(const float* __restrict__ cb,
                     float* __restrict__ c2,
                     double* __restrict__ commits) {
    int row  = blockIdx.x * 4 + (threadIdx.x >> 6);
    int lane = threadIdx.x & 63;
    const float* p = cb + (size_t)row * Dd;
    float a = p[lane], b = p[lane + 64];
    float s = a * a + b * b;
    #pragma unroll
    for (int off = 32; off; off >>= 1) s += __shfl_down(s, off);
    if (lane == 0) c2[row] = s;
    if (blockIdx.x == 0 && threadIdx.x < NQ) commits[threadIdx.x] = 0.0;
}

// ---------------------------------------------------------------------------
// Fused argmin + STE update. 256 threads = 4 waves; 16 points x 1024 codes.
// Wave w owns codes [w*256, +256); lane owns 4 (acc = 16 pts x 2 v2f = 64 VGPR,
// v_pk_fma_f32 -> 2 f32 FMA per instr: issue floor 27.3 us/stage).
// 4 dims per iter; next iter's 4 cbT rows prefetched into registers (breaks
// the L2 load->use stall). Point tile broadcast via ds_read_b128 (conflict-
// free). Accumulation chain per (p,c) is d ascending 0..127 -> bitwise
// identical scores to round 6. First-occurrence argmin: codes ascending in
// (lane c, lane, wave); strict < everywhere; cross-lane tie -> smaller code.
// ---------------------------------------------------------------------------
__global__ __launch_bounds__(256, 4) void k_argmin_fused(
        float* resid,
        const float* __restrict__ cbT,    // (D x K) this stage
        const float* __restrict__ cb,     // (K x D) this stage
        const float* __restrict__ c2,     // (K)     this stage
        float* __restrict__ codes_f,      // offset by q*BT
        double* __restrict__ commit) {
    __shared__ float Rt[PW][132];         // 8448 B, row stride 528 B
    __shared__ float redv[4][PW];
    __shared__ int   redi[4][PW];
    __shared__ int   sidx[PW];
    __shared__ float csum[4];

    int tid  = threadIdx.x;
    int w    = tid >> 6;
    int lane = tid & 63;
    int base = blockIdx.x * PW;

    // stage 16 pts x 128 dims = 512 float4 (coalesced; conflict-light)
    #pragma unroll
    for (int j = 0; j < 2; j++) {
        int f = tid + 256 * j;
        int p = f >> 5, d4 = f & 31;
        float4 v = *(const float4*)&resid[(size_t)(base + p) * Dd + d4 * 4];
        *(float4*)&Rt[p][d4 * 4] = v;
    }
    __syncthreads();

    int cbase = w * 256 + lane * CPL;     // this lane's 4 codes
    v2f accA[PW], accB[PW];               // [p]: (c0,c1) and (c2,c3)
    #pragma unroll
    for (int p = 0; p < PW; p++) {
        accA[p] = (v2f){0.f, 0.f};
        accB[p] = (v2f){0.f, 0.f};
    }

    const float* colbase = cbT + cbase;
    float4 cv0 = *(const float4*)(colbase);
    float4 cv1 = *(const float4*)(colbase + Kk);
    float4 cv2 = *(const float4*)(colbase + 2 * (size_t)Kk);
    float4 cv3 = *(const float4*)(colbase + 3 * (size_t)Kk);

    for (int k4 = 0; k4 < 32; k4++) {     // 4 dims per iteration
        // prefetch next iteration's 4 rows (last iter reloads row 31: benign)
        int nk = (k4 < 31) ? (k4 + 1) : 31;
        const float* ncol = colbase + (size_t)(nk * 4) * Kk;
        float4 nv0 = *(const float4*)(ncol);
        float4 nv1 = *(const float4*)(ncol + Kk);
        float4 nv2 = *(const float4*)(ncol + 2 * (size_t)Kk);
        float4 nv3 = *(const float4*)(ncol + 3 * (size_t)Kk);

        v2f a0 = (v2f){cv0.x, cv0.y}, b0 = (v2f){cv0.z, cv0.w};
        v2f a1 = (v2f){cv1.x, cv1.y}, b1 = (v2f){cv1.z, cv1.w};
        v2f a2 = (v2f){cv2.x, cv2.y}, b2 = (v2f){cv2.z, cv2.w};
        v2f a3 = (v2f){cv3.x, cv3.y}, b3 = (v2f){cv3.z, cv3.w};

        #pragma unroll
        for (int p = 0; p < PW; p++) {
            float4 rv = *(const float4*)&Rt[p][k4 * 4];   // broadcast b128
            v2f r;
            r = (v2f){rv.x, rv.x};
            accA[p] = __builtin_elementwise_fma(r, a0, accA[p]);
            accB[p] = __builtin_elementwise_fma(r, b0, accB[p]);
            r = (v2f){rv.y, rv.y};
            accA[p] = __builtin_elementwise_fma(r, a1, accA[p]);
            accB[p] = __builtin_elementwise_fma(r, b1, accB[p]);
            r = (v2f){rv.z, rv.z};
            accA[p] = __builtin_elementwise_fma(r, a2, accA[p]);
            accB[p] = __builtin_elementwise_fma(r, b2, accB[p]);
            r = (v2f){rv.w, rv.w};
            accA[p] = __builtin_elementwise_fma(r, a3, accA[p]);
            accB[p] = __builtin_elementwise_fma(r, b3, accB[p]);
        }
        cv0 = nv0; cv1 = nv1; cv2 = nv2; cv3 = nv3;
    }

    // epilogue: score = c2 - 2*dot; per-lane min (ascending c, strict <),
    // then wave butterfly (tie -> smaller code), then cross-wave via LDS.
    float4 cc2 = *(const float4*)&c2[cbase];
    #pragma unroll
    for (int p = 0; p < PW; p++) {
        float s0 = fmaf(-2.0f, accA[p].x, cc2.x);
        float s1 = fmaf(-2.0f, accA[p].y, cc2.y);
        float s2 = fmaf(-2.0f, accB[p].x, cc2.z);
        float s3 = fmaf(-2.0f, accB[p].y, cc2.w);
        float v = s0; int ci = 0;
        if (s1 < v) { v = s1; ci = 1; }
        if (s2 < v) { v = s2; ci = 2; }
        if (s3 < v) { v = s3; ci = 3; }
        int i = cbase + ci;
        #pragma unroll
        for (int off = 32; off; off >>= 1) {
            float v2 = __shfl_xor(v, off);
            int   i2 = __shfl_xor(i, off);
            if (v2 < v || (v2 == v && i2 < i)) { v = v2; i = i2; }
        }
        if (lane == 0) { redv[w][p] = v; redi[w][p] = i; }
    }
    __syncthreads();

    // combine 4 waves (ascending code ranges -> strict < keeps first occ.)
    if (tid < PW) {
        float bv = redv[0][tid]; int bi = redi[0][tid];
        #pragma unroll
        for (int w2 = 1; w2 < 4; w2++) {
            float v = redv[w2][tid];
            if (v < bv) { bv = v; bi = redi[w2][tid]; }
        }
        sidx[tid] = bi;
        codes_f[base + tid] = (float)bi;
    }
    __syncthreads();

    // fused STE update: thread -> point tid>>4, dims [ (tid&15)*8, +8 )
    int p    = tid >> 4;
    int dbeg = (tid & 15) * 8;
    float cacc = 0.0f;
    #pragma unroll
    for (int h = 0; h < 2; h++) {
        float4 q = *(const float4*)&cb[(size_t)sidx[p] * Dd + dbeg + h * 4];
        float4 r = *(const float4*)&Rt[p][dbeg + h * 4];
        float t1x = q.x - r.x, t1y = q.y - r.y;
        float t1z = q.z - r.z, t1w = q.w - r.w;     // q - residual
        float qsx = r.x + t1x, qsy = r.y + t1y;
        float qsz = r.z + t1z, qsw = r.w + t1w;     // straight-through value
        float4 nr = make_float4(r.x - qsx, r.y - qsy, r.z - qsz, r.w - qsw);
        *(float4*)&resid[(size_t)(base + p) * Dd + dbeg + h * 4] = nr;
        cacc = fmaf(t1x, t1x, cacc);
        cacc = fmaf(t1y, t1y, cacc);
        cacc = fmaf(t1z, t1z, cacc);
        cacc = fmaf(t1w, t1w, cacc);
    }
    #pragma unroll
    for (int off = 32; off; off >>= 1) cacc += __shfl_down(cacc, off);
    if (lane == 0) csum[w] = cacc;
    __syncthreads();
    if (tid == 0)
        atomicAdd(commit, (double)(csum[0] + csum[1] + csum[2] + csum[3]));
}

// ---------------------------------------------------------------------------
// final: out(B,D,T) = x - resid_final^T
// ---------------------------------------------------------------------------
__global__ void k_final(const float* __restrict__ x,
                        const float* __restrict__ resid,
                        float* __restrict__ outq) {
    __shared__ float tile[32][33];
    int b  = blockIdx.z;
    int t0 = blockIdx.x * 32, d0 = blockIdx.y * 32;
    int tx = threadIdx.x, ty = threadIdx.y;   // 32 x 8
    #pragma unroll
    for (int k = 0; k < 4; k++) {
        int t = t0 + ty + k * 8;
        tile[ty + k * 8][tx] = resid[((size_t)(b * Tt + t)) * Dd + d0 + tx];
    }
    __syncthreads();
    #pragma unroll
    for (int k = 0; k < 4; k++) {
        int d = d0 + ty + k * 8;
        size_t o = ((size_t)(b * Dd + d)) * Tt + t0 + tx;
        outq[o] = x[o] - tile[tx][ty + k * 8];
    }
}

// ---------------------------------------------------------------------------
// scalars: bw = n_q * log2(K) * frame_rate ; penalty = mean(commits)
// ---------------------------------------------------------------------------
__global__ void k_scalars(const double* __restrict__ commits,
                          const int* __restrict__ frame_rate,
                          float* __restrict__ outs) {
    if (threadIdx.x == 0 && blockIdx.x == 0) {
        double s = 0.0;
        #pragma unroll
        for (int q = 0; q < NQ; q++) s += commits[q];
        double per_elem = s / ((double)NQ * (double)BT * (double)Dd);
        outs[0] = (float)(NQ * 10.0 * (double)frame_rate[0]); // log2(1024)=10
        outs[1] = (float)per_elem;
    }
}

extern "C" void kernel_launch(void* const* d_in, const int* in_sizes, int n_in,
                              void* d_out, int out_size, void* d_ws, size_t ws_size,
                              hipStream_t stream) {
    const float* x  = (const float*)d_in[0];   // (B, D, T)
    const float* cb = (const float*)d_in[1];   // (NQ, K, D)
    const int*   fr = (const int*)d_in[2];     // frame_rate

    float* outq    = (float*)d_out;                       // (B,D,T) 4194304
    float* codes_f = outq + (size_t)Bsz * Dd * Tt;        // (NQ,B,T) 262144
    float* scal    = codes_f + (size_t)NQ * BT;           // bw, penalty

    char* ws = (char*)d_ws;
    float*  resid   = (float*)ws;                         // BT*D
    float*  cbT     = resid + (size_t)BT * Dd;            // NQ*D*K
    float*  c2      = cbT + (size_t)NQ * Dd * Kk;         // NQ*K
    double* commits = (double*)(c2 + (size_t)NQ * Kk);    // NQ

    dim3 tb(32, 8, 1);
    k_init<<<dim3(Tt / 32, Dd / 32, Bsz), tb, 0, stream>>>(x, resid);
    k_cbT<<<dim3(Kk / 32, Dd / 32, NQ), tb, 0, stream>>>(cb, cbT);
    k_c2<<<NQ * Kk / 4, 256, 0, stream>>>(cb, c2, commits);

    for (int q = 0; q < NQ; q++) {
        k_argmin_fused<<<BT / PW, 256, 0, stream>>>(
            resid,
            cbT + (size_t)q * Dd * Kk,
            cb  + (size_t)q * Kk * Dd,
            c2  + (size_t)q * Kk,
            codes_f + (size_t)q * BT,
            commits + q);
    }

    k_final<<<dim3(Tt / 32, Dd / 32, Bsz), tb, 0, stream>>>(x, resid, outq);
    k_scalars<<<1, 64, 0, stream>>>(commits, fr, scal);
}

// Round 8
// 1046.784 us; speedup vs baseline: 1.1291x; 1.1291x over previous
//
#include <hip/hip_runtime.h>
#include <math.h>

#define Bsz 8
#define Dd  128
#define Tt  4096
#define Kk  1024
#define NQ  8
#define BT  (Bsz*Tt)        // 32768 points
#define PW  16              // points per block (shared by 4 waves)
#define CPL 4               // codes per lane (64 lanes * 4 = 256 codes/wave)

typedef float v2f __attribute__((ext_vector_type(2)));

// ---------------------------------------------------------------------------
// init: transpose x (B,D,T) -> resid (B,T,D)
// ---------------------------------------------------------------------------
__global__ void k_init(const float* __restrict__ x,
                       float* __restrict__ resid) {
    __shared__ float tile[32][33];
    int b  = blockIdx.z;
    int t0 = blockIdx.x * 32, d0 = blockIdx.y * 32;
    int tx = threadIdx.x, ty = threadIdx.y;   // 32 x 8
    #pragma unroll
    for (int k = 0; k < 4; k++) {
        int d = d0 + ty + k * 8;
        tile[ty + k * 8][tx] = x[((size_t)(b * Dd + d)) * Tt + t0 + tx];
    }
    __syncthreads();
    #pragma unroll
    for (int k = 0; k < 4; k++) {
        int t = t0 + ty + k * 8;
        resid[((size_t)(b * Tt + t)) * Dd + d0 + tx] = tile[tx][ty + k * 8];
    }
}

// ---------------------------------------------------------------------------
// cbT[q][d][k] = cb[q][k][d]  (once; reused by all stages)
// ---------------------------------------------------------------------------
__global__ void k_cbT(const float* __restrict__ cb, float* __restrict__ cbT) {
    __shared__ float tile[32][33];
    int q  = blockIdx.z;
    int k0 = blockIdx.x * 32, d0 = blockIdx.y * 32;
    int tx = threadIdx.x, ty = threadIdx.y;   // 32 x 8
    const float* src = cb  + (size_t)q * Kk * Dd;
    float*       dst = cbT + (size_t)q * Dd * Kk;
    #pragma unroll
    for (int r = 0; r < 4; r++) {
        int k = k0 + ty + r * 8;
        tile[ty + r * 8][tx] = src[(size_t)k * Dd + d0 + tx];
    }
    __syncthreads();
    #pragma unroll
    for (int r = 0; r < 4; r++) {
        int d = d0 + ty + r * 8;
        dst[(size_t)d * Kk + k0 + tx] = tile[tx][ty + r * 8];
    }
}

// ---------------------------------------------------------------------------
// c2[q][k] = sum_d cb[q][k][d]^2 ; zero commit accumulators
// ---------------------------------------------------------------------------
__global__ void k_c2(const float* __restrict__ cb,
                     float* __restrict__ c2,
                     double* __restrict__ commits) {
    int row  = blockIdx.x * 4 + (threadIdx.x >> 6);
    int lane = threadIdx.x & 63;
    const float* p = cb + (size_t)row * Dd;
    float a = p[lane], b = p[lane + 64];
    float s = a * a + b * b;
    #pragma unroll
    for (int off = 32; off; off >>= 1) s += __shfl_down(s, off);
    if (lane == 0) c2[row] = s;
    if (blockIdx.x == 0 && threadIdx.x < NQ) commits[threadIdx.x] = 0.0;
}

// ---------------------------------------------------------------------------
// Fused argmin + STE update. 256 threads = 4 waves; 16 points x 1024 codes.
// Round-6 structure (validated, no spills) with ONE change: the accumulate
// step uses v2f + __builtin_elementwise_fma -> v_pk_fma_f32 (2 f32 FMA per
// instr, halves VALU issue). Same registers (64 floats as 32 pairs), same
// 2-dims-per-iter loads, no prefetch -> liveness == round 6.
// Per-chain accumulation order (d ascending) unchanged -> bitwise-identical
// scores. First-occurrence argmin: codes ascending in (lane c, lane, wave);
// strict < everywhere; cross-lane tie -> smaller code.
// ---------------------------------------------------------------------------
__global__ __launch_bounds__(256, 4) void k_argmin_fused(
        float* resid,
        const float* __restrict__ cbT,    // (D x K) this stage
        const float* __restrict__ cb,     // (K x D) this stage
        const float* __restrict__ c2,     // (K)     this stage
        float* __restrict__ codes_f,      // offset by q*BT
        double* __restrict__ commit) {
    __shared__ float Rt[PW][132];         // 8448 B, row stride 528 B
    __shared__ float redv[4][PW];
    __shared__ int   redi[4][PW];
    __shared__ int   sidx[PW];
    __shared__ float csum[4];

    int tid  = threadIdx.x;
    int w    = tid >> 6;
    int lane = tid & 63;
    int base = blockIdx.x * PW;

    // stage 16 pts x 128 dims = 512 float4 (coalesced; conflict-light)
    #pragma unroll
    for (int j = 0; j < 2; j++) {
        int f = tid + 256 * j;
        int p = f >> 5, d4 = f & 31;
        float4 v = *(const float4*)&resid[(size_t)(base + p) * Dd + d4 * 4];
        *(float4*)&Rt[p][d4 * 4] = v;
    }
    __syncthreads();

    int cbase = w * 256 + lane * CPL;     // this lane's 4 codes
    v2f accA[PW], accB[PW];               // [p]: (c0,c1) and (c2,c3)
    #pragma unroll
    for (int p = 0; p < PW; p++) {
        accA[p] = (v2f){0.f, 0.f};
        accB[p] = (v2f){0.f, 0.f};
    }

    for (int k2 = 0; k2 < 64; k2++) {     // 2 dims per iteration
        const float* col = cbT + (size_t)(k2 * 2) * Kk + cbase;
        float4 cv0 = *(const float4*)(col);
        float4 cv1 = *(const float4*)(col + Kk);
        v2f a0 = (v2f){cv0.x, cv0.y}, b0 = (v2f){cv0.z, cv0.w};
        v2f a1 = (v2f){cv1.x, cv1.y}, b1 = (v2f){cv1.z, cv1.w};
        #pragma unroll
        for (int p = 0; p < PW; p++) {
            float2 rv = *(const float2*)&Rt[p][k2 * 2];   // broadcast b64
            v2f rx = (v2f){rv.x, rv.x};
            accA[p] = __builtin_elementwise_fma(rx, a0, accA[p]);
            accB[p] = __builtin_elementwise_fma(rx, b0, accB[p]);
            v2f ry = (v2f){rv.y, rv.y};
            accA[p] = __builtin_elementwise_fma(ry, a1, accA[p]);
            accB[p] = __builtin_elementwise_fma(ry, b1, accB[p]);
        }
    }

    // epilogue: score = c2 - 2*dot; per-lane min (ascending c, strict <),
    // then wave butterfly (tie -> smaller code), then cross-wave via LDS.
    float4 cc2 = *(const float4*)&c2[cbase];
    #pragma unroll
    for (int p = 0; p < PW; p++) {
        float s0 = fmaf(-2.0f, accA[p].x, cc2.x);
        float s1 = fmaf(-2.0f, accA[p].y, cc2.y);
        float s2 = fmaf(-2.0f, accB[p].x, cc2.z);
        float s3 = fmaf(-2.0f, accB[p].y, cc2.w);
        float v = s0; int ci = 0;
        if (s1 < v) { v = s1; ci = 1; }
        if (s2 < v) { v = s2; ci = 2; }
        if (s3 < v) { v = s3; ci = 3; }
        int i = cbase + ci;
        #pragma unroll
        for (int off = 32; off; off >>= 1) {
            float v2 = __shfl_xor(v, off);
            int   i2 = __shfl_xor(i, off);
            if (v2 < v || (v2 == v && i2 < i)) { v = v2; i = i2; }
        }
        if (lane == 0) { redv[w][p] = v; redi[w][p] = i; }
    }
    __syncthreads();

    // combine 4 waves (ascending code ranges -> strict < keeps first occ.)
    if (tid < PW) {
        float bv = redv[0][tid]; int bi = redi[0][tid];
        #pragma unroll
        for (int w2 = 1; w2 < 4; w2++) {
            float v = redv[w2][tid];
            if (v < bv) { bv = v; bi = redi[w2][tid]; }
        }
        sidx[tid] = bi;
        codes_f[base + tid] = (float)bi;
    }
    __syncthreads();

    // fused STE update: thread -> point tid>>4, dims [ (tid&15)*8, +8 )
    int p    = tid >> 4;
    int dbeg = (tid & 15) * 8;
    float cacc = 0.0f;
    #pragma unroll
    for (int h = 0; h < 2; h++) {
        float4 q = *(const float4*)&cb[(size_t)sidx[p] * Dd + dbeg + h * 4];
        float4 r = *(const float4*)&Rt[p][dbeg + h * 4];
        float t1x = q.x - r.x, t1y = q.y - r.y;
        float t1z = q.z - r.z, t1w = q.w - r.w;     // q - residual
        float qsx = r.x + t1x, qsy = r.y + t1y;
        float qsz = r.z + t1z, qsw = r.w + t1w;     // straight-through value
        float4 nr = make_float4(r.x - qsx, r.y - qsy, r.z - qsz, r.w - qsw);
        *(float4*)&resid[(size_t)(base + p) * Dd + dbeg + h * 4] = nr;
        cacc = fmaf(t1x, t1x, cacc);
        cacc = fmaf(t1y, t1y, cacc);
        cacc = fmaf(t1z, t1z, cacc);
        cacc = fmaf(t1w, t1w, cacc);
    }
    #pragma unroll
    for (int off = 32; off; off >>= 1) cacc += __shfl_down(cacc, off);
    if (lane == 0) csum[w] = cacc;
    __syncthreads();
    if (tid == 0)
        atomicAdd(commit, (double)(csum[0] + csum[1] + csum[2] + csum[3]));
}

// ---------------------------------------------------------------------------
// final: out(B,D,T) = x - resid_final^T
// ---------------------------------------------------------------------------
__global__ void k_final(const float* __restrict__ x,
                        const float* __restrict__ resid,
                        float* __restrict__ outq) {
    __shared__ float tile[32][33];
    int b  = blockIdx.z;
    int t0 = blockIdx.x * 32, d0 = blockIdx.y * 32;
    int tx = threadIdx.x, ty = threadIdx.y;   // 32 x 8
    #pragma unroll
    for (int k = 0; k < 4; k++) {
        int t = t0 + ty + k * 8;
        tile[ty + k * 8][tx] = resid[((size_t)(b * Tt + t)) * Dd + d0 + tx];
    }
    __syncthreads();
    #pragma unroll
    for (int k = 0; k < 4; k++) {
        int d = d0 + ty + k * 8;
        size_t o = ((size_t)(b * Dd + d)) * Tt + t0 + tx;
        outq[o] = x[o] - tile[tx][ty + k * 8];
    }
}

// ---------------------------------------------------------------------------
// scalars: bw = n_q * log2(K) * frame_rate ; penalty = mean(commits)
// ---------------------------------------------------------------------------
__global__ void k_scalars(const double* __restrict__ commits,
                          const int* __restrict__ frame_rate,
                          float* __restrict__ outs) {
    if (threadIdx.x == 0 && blockIdx.x == 0) {
        double s = 0.0;
        #pragma unroll
        for (int q = 0; q < NQ; q++) s += commits[q];
        double per_elem = s / ((double)NQ * (double)BT * (double)Dd);
        outs[0] = (float)(NQ * 10.0 * (double)frame_rate[0]); // log2(1024)=10
        outs[1] = (float)per_elem;
    }
}

extern "C" void kernel_launch(void* const* d_in, const int* in_sizes, int n_in,
                              void* d_out, int out_size, void* d_ws, size_t ws_size,
                              hipStream_t stream) {
    const float* x  = (const float*)d_in[0];   // (B, D, T)
    const float* cb = (const float*)d_in[1];   // (NQ, K, D)
    const int*   fr = (const int*)d_in[2];     // frame_rate

    float* outq    = (float*)d_out;                       // (B,D,T) 4194304
    float* codes_f = outq + (size_t)Bsz * Dd * Tt;        // (NQ,B,T) 262144
    float* scal    = codes_f + (size_t)NQ * BT;           // bw, penalty

    char* ws = (char*)d_ws;
    float*  resid   = (float*)ws;                         // BT*D
    float*  cbT     = resid + (size_t)BT * Dd;            // NQ*D*K
    float*  c2      = cbT + (size_t)NQ * Dd * Kk;         // NQ*K
    double* commits = (double*)(c2 + (size_t)NQ * Kk);    // NQ

    dim3 tb(32, 8, 1);
    k_init<<<dim3(Tt / 32, Dd / 32, Bsz), tb, 0, stream>>>(x, resid);
    k_cbT<<<dim3(Kk / 32, Dd / 32, NQ), tb, 0, stream>>>(cb, cbT);
    k_c2<<<NQ * Kk / 4, 256, 0, stream>>>(cb, c2, commits);

    for (int q = 0; q < NQ; q++) {
        k_argmin_fused<<<BT / PW, 256, 0, stream>>>(
            resid,
            cbT + (size_t)q * Dd * Kk,
            cb  + (size_t)q * Kk * Dd,
            c2  + (size_t)q * Kk,
            codes_f + (size_t)q * BT,
            commits + q);
    }

    k_final<<<dim3(Tt / 32, Dd / 32, Bsz), tb, 0, stream>>>(x, resid, outq);
    k_scalars<<<1, 64, 0, stream>>>(commits, fr, scal);
}

// Round 9
// 746.428 us; speedup vs baseline: 1.5834x; 1.4024x over previous
//
#include <hip/hip_runtime.h>
#include <math.h>

#define Bsz 8
#define Dd  128
#define Tt  4096
#define Kk  1024
#define NQ  8
#define BT  (Bsz*Tt)        // 32768 points
#define MT  64              // points per block (4 waves x 16)
#define DELTA 0.05f         // >= 2x rigorous |approx-exact| score bound (~5e-3)

typedef float f32x4 __attribute__((ext_vector_type(4)));
typedef short short8 __attribute__((ext_vector_type(8)));

__device__ __forceinline__ unsigned short f2bf(float x) {   // RNE f32->bf16
    unsigned u = __float_as_uint(x);
    u += 0x7FFF + ((u >> 16) & 1);
    return (unsigned short)(u >> 16);
}
__device__ __forceinline__ float bf2f(unsigned short h) {
    return __uint_as_float(((unsigned)h) << 16);
}

// ---------------------------------------------------------------------------
// init: transpose x (B,D,T) -> resid (B,T,D)
// ---------------------------------------------------------------------------
__global__ void k_init(const float* __restrict__ x,
                       float* __restrict__ resid) {
    __shared__ float tile[32][33];
    int b  = blockIdx.z;
    int t0 = blockIdx.x * 32, d0 = blockIdx.y * 32;
    int tx = threadIdx.x, ty = threadIdx.y;   // 32 x 8
    #pragma unroll
    for (int k = 0; k < 4; k++) {
        int d = d0 + ty + k * 8;
        tile[ty + k * 8][tx] = x[((size_t)(b * Dd + d)) * Tt + t0 + tx];
    }
    __syncthreads();
    #pragma unroll
    for (int k = 0; k < 4; k++) {
        int t = t0 + ty + k * 8;
        resid[((size_t)(b * Tt + t)) * Dd + d0 + tx] = tile[tx][ty + k * 8];
    }
}

// ---------------------------------------------------------------------------
// k_prep: split codebook into hi/lo bf16, pre-swizzled into MFMA B-fragment
// order. B-frag (16x16x32 bf16): lane holds col n=lane&15, k=quad*8+j.
// Layout per (q, tile): 8192 B = [ch kc0..3 (1KB each) | cl kc0..3].
// ---------------------------------------------------------------------------
__global__ void k_prep(const float* __restrict__ cb, char* __restrict__ bswz) {
    int ln = threadIdx.x;                 // 64
    int kc = blockIdx.x & 3;
    int t  = (blockIdx.x >> 2) & 63;
    int q  = blockIdx.x >> 8;
    int code = t * 16 + (ln & 15);
    int d0   = kc * 32 + (ln >> 4) * 8;
    const float* src = cb + ((size_t)(q * Kk + code)) * Dd + d0;
    float v[8];
    *(float4*)&v[0] = *(const float4*)src;
    *(float4*)&v[4] = *(const float4*)(src + 4);
    short8 h, l;
    #pragma unroll
    for (int j = 0; j < 8; j++) {
        unsigned short hu = f2bf(v[j]);
        h[j] = (short)hu;
        l[j] = (short)f2bf(v[j] - bf2f(hu));   // exact remainder, then RNE
    }
    char* base = bswz + ((size_t)(q * 64 + t)) * 8192;
    *(short8*)(base + kc * 1024 + ln * 16) = h;
    *(short8*)(base + 4096 + kc * 1024 + ln * 16) = l;
}

// ---------------------------------------------------------------------------
// c2[q][k] = sum_d cb[q][k][d]^2 (exact f32) ; zero commit accumulators
// ---------------------------------------------------------------------------
__global__ void k_c2(const float* __restrict__ cb,
                     float* __restrict__ c2,
                     double* __restrict__ commits) {
    int row  = blockIdx.x * 4 + (threadIdx.x >> 6);
    int lane = threadIdx.x & 63;
    const float* p = cb + (size_t)row * Dd;
    float a = p[lane], b = p[lane + 64];
    float s = a * a + b * b;
    #pragma unroll
    for (int off = 32; off; off >>= 1) s += __shfl_down(s, off);
    if (lane == 0) c2[row] = s;
    if (blockIdx.x == 0 && threadIdx.x < NQ) commits[threadIdx.x] = 0.0;
}

// exact f32 chain, d ascending — identical to the validated round-6 order
__device__ __forceinline__ float exact_score(const float* __restrict__ rrow,
                                             const float* __restrict__ crow,
                                             float c2v) {
    float a = 0.0f;
    #pragma unroll
    for (int d4 = 0; d4 < 32; d4++) {
        float4 r = *(const float4*)(rrow + d4 * 4);
        float4 c = *(const float4*)(crow + d4 * 4);
        a = fmaf(r.x, c.x, a); a = fmaf(r.y, c.y, a);
        a = fmaf(r.z, c.z, a); a = fmaf(r.w, c.w, a);
    }
    return fmaf(-2.0f, a, c2v);
}

// ---------------------------------------------------------------------------
// MFMA argmin (split-bf16 filter + exact f32 rescore) + fused STE update.
// Block = 256 thr = 4 waves; 64 points x 1024 codes.
// Pass 1 (tiles 0..63): approx score = c2 - 2*(rl.ch + rh.cl + rh.ch),
// running min per point. Pass 2: collect candidates <= min + DELTA.
// Rescore candidates with exact_score (first-occurrence tie-break), then
// STE update + commit. Candidate set provably contains every exact argmin.
// ---------------------------------------------------------------------------
__global__ __launch_bounds__(256, 2) void k_argmin_mfma(
        float* resid,
        const float*  __restrict__ cb,     // (K x D) f32 this stage
        const float4* __restrict__ bswzq,  // swizzled split frags this stage
        const float*  __restrict__ c2g,    // (K) exact f32
        float* __restrict__ codes_f,       // offset by q*BT
        double* __restrict__ commit) {
    __shared__ float4 Bst[2][512];         // double-buffered tile frags 16KB
    __shared__ float  c2s[Kk];             // 4KB
    __shared__ int    cnt[MT];
    __shared__ int    cand[MT][16];
    __shared__ int    sidxs[MT];
    __shared__ float  csum[4];

    int tid  = threadIdx.x;
    int w    = tid >> 6, ln = tid & 63;
    int quad = ln >> 4,  m  = ln & 15;
    int base = blockIdx.x * MT;

    for (int i = tid; i < Kk; i += 256) c2s[i] = c2g[i];

    // A-fragments for this wave's 16 points: A[m=lane&15][k=quad*8+j]
    short8 Ah[4], Al[4];
    {
        const float* rrow = resid + ((size_t)(base + w * 16 + m)) * Dd;
        #pragma unroll
        for (int kc = 0; kc < 4; kc++) {
            int d0 = kc * 32 + quad * 8;
            float v[8];
            *(float4*)&v[0] = *(const float4*)(rrow + d0);
            *(float4*)&v[4] = *(const float4*)(rrow + d0 + 4);
            short8 h, l;
            #pragma unroll
            for (int j = 0; j < 8; j++) {
                unsigned short hu = f2bf(v[j]);
                h[j] = (short)hu;
                l[j] = (short)f2bf(v[j] - bf2f(hu));
            }
            Ah[kc] = h; Al[kc] = l;
        }
    }

    // prestage tile 0
    Bst[0][tid]       = bswzq[tid];
    Bst[0][tid + 256] = bswzq[tid + 256];
    __syncthreads();

    float best[4] = {INFINITY, INFINITY, INFINITY, INFINITY};
    float thr[4]  = {0.f, 0.f, 0.f, 0.f};

    for (int s = 0; s < 128; s++) {        // 2 passes x 64 tiles
        int t = s & 63, buf = s & 1;
        bool more = (s < 127);
        float4 g0, g1;
        if (more) {                         // load next tile early
            const float4* src = bswzq + (size_t)((s + 1) & 63) * 512;
            g0 = src[tid]; g1 = src[tid + 256];
        }
        const short8* Bp = (const short8*)&Bst[buf][0];
        f32x4 acc01 = {0.f, 0.f, 0.f, 0.f};
        f32x4 acc23 = {0.f, 0.f, 0.f, 0.f};
        #pragma unroll
        for (int kc = 0; kc < 4; kc++) {
            short8 ch = Bp[kc * 64 + ln];
            short8 cl = Bp[256 + kc * 64 + ln];
            if (kc < 2) {
                acc01 = __builtin_amdgcn_mfma_f32_16x16x32_bf16(Al[kc], ch, acc01, 0, 0, 0);
                acc01 = __builtin_amdgcn_mfma_f32_16x16x32_bf16(Ah[kc], cl, acc01, 0, 0, 0);
                acc01 = __builtin_amdgcn_mfma_f32_16x16x32_bf16(Ah[kc], ch, acc01, 0, 0, 0);
            } else {
                acc23 = __builtin_amdgcn_mfma_f32_16x16x32_bf16(Al[kc], ch, acc23, 0, 0, 0);
                acc23 = __builtin_amdgcn_mfma_f32_16x16x32_bf16(Ah[kc], cl, acc23, 0, 0, 0);
                acc23 = __builtin_amdgcn_mfma_f32_16x16x32_bf16(Ah[kc], ch, acc23, 0, 0, 0);
            }
        }
        float c2v = c2s[t * 16 + m];       // lane's code col
        if (s < 64) {
            #pragma unroll
            for (int j = 0; j < 4; j++) {
                float sc = fmaf(-2.0f, acc01[j] + acc23[j], c2v);
                best[j] = fminf(best[j], sc);
            }
        } else {
            #pragma unroll
            for (int j = 0; j < 4; j++) {
                float sc = fmaf(-2.0f, acc01[j] + acc23[j], c2v);
                if (sc <= thr[j]) {
                    int p  = w * 16 + quad * 4 + j;
                    int sl = atomicAdd(&cnt[p], 1);
                    if (sl < 16) cand[p][sl] = t * 16 + m;
                }
            }
        }
        if (s == 63) {                      // per-point approx min + reset cnt
            #pragma unroll
            for (int j = 0; j < 4; j++) {
                float v = best[j];
                #pragma unroll
                for (int off = 1; off < 16; off <<= 1)
                    v = fminf(v, __shfl_xor(v, off));   // reduce over 16 cols
                thr[j] = v + DELTA;
            }
            if (tid < MT) cnt[tid] = 0;
        }
        if (more) {
            Bst[buf ^ 1][tid]       = g0;
            Bst[buf ^ 1][tid + 256] = g1;
        }
        __syncthreads();
    }

    // exact rescore of candidates (thread per point)
    if (tid < MT) {
        int p = tid, n = cnt[p];
        const float* rrow = resid + ((size_t)(base + p)) * Dd;
        float bv = INFINITY; int bk = 0;
        if (n <= 16) {
            for (int si = 0; si < n; si++) {
                int k = cand[p][si];
                float sc = exact_score(rrow, cb + (size_t)k * Dd, c2s[k]);
                if (sc < bv || (sc == bv && k < bk)) { bv = sc; bk = k; }
            }
        } else {                            // overflow (~never): full exact scan
            for (int k = 0; k < Kk; k++) {
                float sc = exact_score(rrow, cb + (size_t)k * Dd, c2s[k]);
                if (sc < bv) { bv = sc; bk = k; }
            }
        }
        sidxs[p] = bk;
        codes_f[base + p] = (float)bk;
    }
    __syncthreads();

    // fused STE update: thread -> point tid>>2, dims [(tid&3)*32, +32)
    {
        int p = tid >> 2, dbeg = (tid & 3) * 32;
        float* rrow = resid + ((size_t)(base + p)) * Dd + dbeg;
        const float* qrow = cb + ((size_t)sidxs[p]) * Dd + dbeg;
        float cacc = 0.0f;
        #pragma unroll
        for (int hh = 0; hh < 8; hh++) {
            float4 r  = *(const float4*)(rrow + hh * 4);
            float4 qv = *(const float4*)(qrow + hh * 4);
            float t1x = qv.x - r.x, t1y = qv.y - r.y;
            float t1z = qv.z - r.z, t1w = qv.w - r.w;    // q - residual
            float qsx = r.x + t1x, qsy = r.y + t1y;
            float qsz = r.z + t1z, qsw = r.w + t1w;      // straight-through
            float4 nr = make_float4(r.x - qsx, r.y - qsy, r.z - qsz, r.w - qsw);
            *(float4*)(rrow + hh * 4) = nr;
            cacc = fmaf(t1x, t1x, cacc); cacc = fmaf(t1y, t1y, cacc);
            cacc = fmaf(t1z, t1z, cacc); cacc = fmaf(t1w, t1w, cacc);
        }
        #pragma unroll
        for (int off = 32; off; off >>= 1) cacc += __shfl_down(cacc, off);
        if (ln == 0) csum[w] = cacc;
    }
    __syncthreads();
    if (tid == 0)
        atomicAdd(commit, (double)(csum[0] + csum[1] + csum[2] + csum[3]));
}

// ---------------------------------------------------------------------------
// final: out(B,D,T) = x - resid_final^T
// ---------------------------------------------------------------------------
__global__ void k_final(const float* __restrict__ x,
                        const float* __restrict__ resid,
                        float* __restrict__ outq) {
    __shared__ float tile[32][33];
    int b  = blockIdx.z;
    int t0 = blockIdx.x * 32, d0 = blockIdx.y * 32;
    int tx = threadIdx.x, ty = threadIdx.y;   // 32 x 8
    #pragma unroll
    for (int k = 0; k < 4; k++) {
        int t = t0 + ty + k * 8;
        tile[ty + k * 8][tx] = resid[((size_t)(b * Tt + t)) * Dd + d0 + tx];
    }
    __syncthreads();
    #pragma unroll
    for (int k = 0; k < 4; k++) {
        int d = d0 + ty + k * 8;
        size_t o = ((size_t)(b * Dd + d)) * Tt + t0 + tx;
        outq[o] = x[o] - tile[tx][ty + k * 8];
    }
}

// ---------------------------------------------------------------------------
// scalars: bw = n_q * log2(K) * frame_rate ; penalty = mean(commits)
// ---------------------------------------------------------------------------
__global__ void k_scalars(const double* __restrict__ commits,
                          const int* __restrict__ frame_rate,
                          float* __restrict__ outs) {
    if (threadIdx.x == 0 && blockIdx.x == 0) {
        double s = 0.0;
        #pragma unroll
        for (int q = 0; q < NQ; q++) s += commits[q];
        double per_elem = s / ((double)NQ * (double)BT * (double)Dd);
        outs[0] = (float)(NQ * 10.0 * (double)frame_rate[0]); // log2(1024)=10
        outs[1] = (float)per_elem;
    }
}

extern "C" void kernel_launch(void* const* d_in, const int* in_sizes, int n_in,
                              void* d_out, int out_size, void* d_ws, size_t ws_size,
                              hipStream_t stream) {
    const float* x  = (const float*)d_in[0];   // (B, D, T)
    const float* cb = (const float*)d_in[1];   // (NQ, K, D)
    const int*   fr = (const int*)d_in[2];     // frame_rate

    float* outq    = (float*)d_out;                       // (B,D,T) 4194304
    float* codes_f = outq + (size_t)Bsz * Dd * Tt;        // (NQ,B,T) 262144
    float* scal    = codes_f + (size_t)NQ * BT;           // bw, penalty

    char* ws = (char*)d_ws;
    float*  resid   = (float*)ws;                              // BT*D f32
    float*  c2      = resid + (size_t)BT * Dd;                 // NQ*K f32
    double* commits = (double*)(c2 + (size_t)NQ * Kk);         // NQ f64
    char*   bswz    = (char*)(commits + NQ);                   // NQ*64*8192 B

    dim3 tb(32, 8, 1);
    k_init<<<dim3(Tt / 32, Dd / 32, Bsz), tb, 0, stream>>>(x, resid);
    k_prep<<<NQ * 256, 64, 0, stream>>>(cb, bswz);
    k_c2<<<NQ * Kk / 4, 256, 0, stream>>>(cb, c2, commits);

    for (int q = 0; q < NQ; q++) {
        k_argmin_mfma<<<BT / MT, 256, 0, stream>>>(
            resid,
            cb + (size_t)q * Kk * Dd,
            (const float4*)(bswz + (size_t)q * 64 * 8192),
            c2 + (size_t)q * Kk,
            codes_f + (size_t)q * BT,
            commits + q);
    }

    k_final<<<dim3(Tt / 32, Dd / 32, Bsz), tb, 0, stream>>>(x, resid, outq);
    k_scalars<<<1, 64, 0, stream>>>(commits, fr, scal);
}

// Round 10
// 692.117 us; speedup vs baseline: 1.7077x; 1.0785x over previous
//
#include <hip/hip_runtime.h>
#include <math.h>

#define Bsz 8
#define Dd  128
#define Tt  4096
#define Kk  1024
#define NQ  8
#define BT  (Bsz*Tt)        // 32768 points
#define MT  64              // points per block (4 waves x 16)
#define DELTA 0.05f         // >= 10x rigorous |approx-exact| score bound

typedef float f32x4 __attribute__((ext_vector_type(4)));
typedef short short8 __attribute__((ext_vector_type(8)));

__device__ __forceinline__ unsigned short f2bf(float x) {   // RNE f32->bf16
    unsigned u = __float_as_uint(x);
    u += 0x7FFF + ((u >> 16) & 1);
    return (unsigned short)(u >> 16);
}
__device__ __forceinline__ float bf2f(unsigned short h) {
    return __uint_as_float(((unsigned)h) << 16);
}

// ---------------------------------------------------------------------------
// init: transpose x (B,D,T) -> resid (B,T,D)
// ---------------------------------------------------------------------------
__global__ void k_init(const float* __restrict__ x,
                       float* __restrict__ resid) {
    __shared__ float tile[32][33];
    int b  = blockIdx.z;
    int t0 = blockIdx.x * 32, d0 = blockIdx.y * 32;
    int tx = threadIdx.x, ty = threadIdx.y;   // 32 x 8
    #pragma unroll
    for (int k = 0; k < 4; k++) {
        int d = d0 + ty + k * 8;
        tile[ty + k * 8][tx] = x[((size_t)(b * Dd + d)) * Tt + t0 + tx];
    }
    __syncthreads();
    #pragma unroll
    for (int k = 0; k < 4; k++) {
        int t = t0 + ty + k * 8;
        resid[((size_t)(b * Tt + t)) * Dd + d0 + tx] = tile[tx][ty + k * 8];
    }
}

// ---------------------------------------------------------------------------
// k_prep: split codebook into hi/lo bf16, pre-swizzled into MFMA B-fragment
// order. B-frag (16x16x32 bf16): lane holds col n=lane&15, k=quad*8+j.
// Layout per (q, tile): 8192 B = [ch kc0..3 (1KB each) | cl kc0..3].
// ---------------------------------------------------------------------------
__global__ void k_prep(const float* __restrict__ cb, char* __restrict__ bswz) {
    int ln = threadIdx.x;                 // 64
    int kc = blockIdx.x & 3;
    int t  = (blockIdx.x >> 2) & 63;
    int q  = blockIdx.x >> 8;
    int code = t * 16 + (ln & 15);
    int d0   = kc * 32 + (ln >> 4) * 8;
    const float* src = cb + ((size_t)(q * Kk + code)) * Dd + d0;
    float v[8];
    *(float4*)&v[0] = *(const float4*)src;
    *(float4*)&v[4] = *(const float4*)(src + 4);
    short8 h, l;
    #pragma unroll
    for (int j = 0; j < 8; j++) {
        unsigned short hu = f2bf(v[j]);
        h[j] = (short)hu;
        l[j] = (short)f2bf(v[j] - bf2f(hu));   // exact remainder, then RNE
    }
    char* base = bswz + ((size_t)(q * 64 + t)) * 8192;
    *(short8*)(base + kc * 1024 + ln * 16) = h;
    *(short8*)(base + 4096 + kc * 1024 + ln * 16) = l;
}

// ---------------------------------------------------------------------------
// c2[q][k] = sum_d cb[q][k][d]^2 (exact f32) ; zero commit accumulators
// ---------------------------------------------------------------------------
__global__ void k_c2(const float* __restrict__ cb,
                     float* __restrict__ c2,
                     double* __restrict__ commits) {
    int row  = blockIdx.x * 4 + (threadIdx.x >> 6);
    int lane = threadIdx.x & 63;
    const float* p = cb + (size_t)row * Dd;
    float a = p[lane], b = p[lane + 64];
    float s = a * a + b * b;
    #pragma unroll
    for (int off = 32; off; off >>= 1) s += __shfl_down(s, off);
    if (lane == 0) c2[row] = s;
    if (blockIdx.x == 0 && threadIdx.x < NQ) commits[threadIdx.x] = 0.0;
}

// exact f32 chain, d ascending — identical to the validated round-6 order
__device__ __forceinline__ float exact_score(const float* __restrict__ rrow,
                                             const float* __restrict__ crow,
                                             float c2v) {
    float a = 0.0f;
    #pragma unroll
    for (int d4 = 0; d4 < 32; d4++) {
        float4 r = *(const float4*)(rrow + d4 * 4);
        float4 c = *(const float4*)(crow + d4 * 4);
        a = fmaf(r.x, c.x, a); a = fmaf(r.y, c.y, a);
        a = fmaf(r.z, c.z, a); a = fmaf(r.w, c.w, a);
    }
    return fmaf(-2.0f, a, c2v);
}

// ---------------------------------------------------------------------------
// MFMA argmin, single pass. Block = 256 thr = 4 waves; 64 pts x 1024 codes.
// B-fragments stream from L2 (global, pre-swizzled) into registers with
// next-tile prefetch — NO LDS / NO barriers in the hot loop.
// Per-lane top-3 (values; indices for top-2) over its 64 codes; cross-lane
// merge of sorted triples -> global top-3 per point. Certification:
// b3 > b1+DELTA  =>  candidate set (all codes with approx <= b1+DELTA,
// which provably contains every exact argmin and its ties) is within
// {i1,i2}; exact f32 rescore of <=2 candidates with index tie-break =>
// codes exact by construction. Else: rare block-cooperative exact scan.
// ---------------------------------------------------------------------------
__global__ __launch_bounds__(256, 2) void k_argmin_mfma(
        float* resid,
        const float* __restrict__ cb,      // (K x D) f32 this stage
        const char*  __restrict__ bswzq,   // swizzled split frags this stage
        const float* __restrict__ c2g,     // (K) exact f32
        float* __restrict__ codes_f,       // offset by q*BT
        double* __restrict__ commit) {
    __shared__ float c2s[Kk];              // 4 KB
    __shared__ float fb1[MT], fb2[MT], fb3[MT];
    __shared__ int   fi1[MT], fi2[MT];
    __shared__ int   sidxs[MT];
    __shared__ int   nfall, flist[MT];
    __shared__ float fwv[4]; __shared__ int fwi[4];
    __shared__ float csum[4];

    int tid  = threadIdx.x;
    int w    = tid >> 6, ln = tid & 63;
    int quad = ln >> 4,  m  = ln & 15;
    int base = blockIdx.x * MT;

    for (int i = tid; i < Kk; i += 256) c2s[i] = c2g[i];
    if (tid == 0) nfall = 0;

    // A-fragments for this wave's 16 points: A[m=lane&15][k=quad*8+j]
    short8 Ah[4], Al[4];
    {
        const float* rrow = resid + ((size_t)(base + w * 16 + m)) * Dd;
        #pragma unroll
        for (int kc = 0; kc < 4; kc++) {
            int d0 = kc * 32 + quad * 8;
            float v[8];
            *(float4*)&v[0] = *(const float4*)(rrow + d0);
            *(float4*)&v[4] = *(const float4*)(rrow + d0 + 4);
            short8 h, l;
            #pragma unroll
            for (int j = 0; j < 8; j++) {
                unsigned short hu = f2bf(v[j]);
                h[j] = (short)hu;
                l[j] = (short)f2bf(v[j] - bf2f(hu));
            }
            Ah[kc] = h; Al[kc] = l;
        }
    }
    __syncthreads();   // c2s ready

    // per-lane top-3 state per j-slot (4 points per lane)
    float b1[4], b2[4], b3[4]; int i1[4], i2[4];
    #pragma unroll
    for (int j = 0; j < 4; j++) {
        b1[j] = INFINITY; b2[j] = INFINITY; b3[j] = INFINITY;
        i1[j] = 0; i2[j] = 0;
    }

    const short8* Bg = (const short8*)bswzq;   // 512 short8 per tile
    short8 cur[8], nxt[8];
    #pragma unroll
    for (int c = 0; c < 4; c++) {
        cur[c]     = Bg[c * 64 + ln];
        cur[4 + c] = Bg[256 + c * 64 + ln];
    }

    for (int t = 0; t < 64; t++) {
        if (t < 63) {                          // prefetch next tile
            const short8* Bn = Bg + (size_t)(t + 1) * 512;
            #pragma unroll
            for (int c = 0; c < 4; c++) {
                nxt[c]     = Bn[c * 64 + ln];
                nxt[4 + c] = Bn[256 + c * 64 + ln];
            }
        }
        f32x4 acc01 = {0.f, 0.f, 0.f, 0.f};
        f32x4 acc23 = {0.f, 0.f, 0.f, 0.f};
        #pragma unroll
        for (int kc = 0; kc < 4; kc++) {
            short8 ch = cur[kc], cl = cur[4 + kc];
            if (kc < 2) {
                acc01 = __builtin_amdgcn_mfma_f32_16x16x32_bf16(Al[kc], ch, acc01, 0, 0, 0);
                acc01 = __builtin_amdgcn_mfma_f32_16x16x32_bf16(Ah[kc], cl, acc01, 0, 0, 0);
                acc01 = __builtin_amdgcn_mfma_f32_16x16x32_bf16(Ah[kc], ch, acc01, 0, 0, 0);
            } else {
                acc23 = __builtin_amdgcn_mfma_f32_16x16x32_bf16(Al[kc], ch, acc23, 0, 0, 0);
                acc23 = __builtin_amdgcn_mfma_f32_16x16x32_bf16(Ah[kc], cl, acc23, 0, 0, 0);
                acc23 = __builtin_amdgcn_mfma_f32_16x16x32_bf16(Ah[kc], ch, acc23, 0, 0, 0);
            }
        }
        float c2v = c2s[t * 16 + m];
        int   code = t * 16 + m;               // ascending in t per lane
        #pragma unroll
        for (int j = 0; j < 4; j++) {
            float s = fmaf(-2.0f, acc01[j] + acc23[j], c2v);
            bool lt1 = s < b1[j];
            bool lt2 = s < b2[j];
            float t1 = fmaxf(b1[j], s);
            b3[j] = fminf(b3[j], fmaxf(b2[j], t1));
            i2[j] = lt1 ? i1[j] : (lt2 ? code : i2[j]);
            b2[j] = fminf(b2[j], t1);
            i1[j] = lt1 ? code : i1[j];
            b1[j] = fminf(b1[j], s);
        }
        #pragma unroll
        for (int c = 0; c < 8; c++) cur[c] = nxt[c];
    }

    // cross-lane merge of sorted triples over the 16 cols (xor 1,2,4,8)
    #pragma unroll
    for (int j = 0; j < 4; j++) {
        float v1 = b1[j], v2 = b2[j], v3 = b3[j];
        int   a1 = i1[j], a2 = i2[j];
        #pragma unroll
        for (int off = 1; off < 16; off <<= 1) {
            float w1 = __shfl_xor(v1, off); int j1 = __shfl_xor(a1, off);
            float w2 = __shfl_xor(v2, off); int j2 = __shfl_xor(a2, off);
            float w3 = __shfl_xor(v3, off);
            bool aw = (v1 < w1) || (v1 == w1 && a1 < j1);
            float x1 = aw ? v1 : w1, x2 = aw ? v2 : w2, x3 = aw ? v3 : w3;
            int   y1 = aw ? a1 : j1, y2 = aw ? a2 : j2;
            float z1 = aw ? w1 : v1, z2 = aw ? w2 : v2;
            int   u1 = aw ? j1 : a1;
            // merged: 1st = x1; 2nd = min(x2, z1); 3rd per case
            bool s2a = (x2 < z1) || (x2 == z1 && y2 < u1);
            v1 = x1; a1 = y1;
            v2 = s2a ? x2 : z1; a2 = s2a ? y2 : u1;
            v3 = s2a ? fminf(x3, z1) : fminf(x2, z2);
        }
        if (m == 0) {
            int p = w * 16 + quad * 4 + j;
            fb1[p] = v1; fb2[p] = v2; fb3[p] = v3;
            fi1[p] = a1; fi2[p] = a2;
        }
    }
    __syncthreads();

    // decision + exact rescore of <=2 candidates (thread per point)
    if (tid < MT) {
        int p = tid;
        float v1 = fb1[p], v2 = fb2[p], v3 = fb3[p];
        int   a1 = fi1[p], a2 = fi2[p];
        if (v3 <= v1 + DELTA) {
            int sl = atomicAdd(&nfall, 1);     // rare: >=3 in window
            flist[sl] = p;
        } else {
            int bk = a1;
            if (v2 <= v1 + DELTA) {            // two candidates: rescore both
                const float* rrow = resid + ((size_t)(base + p)) * Dd;
                float s1 = exact_score(rrow, cb + (size_t)a1 * Dd, c2s[a1]);
                float s2 = exact_score(rrow, cb + (size_t)a2 * Dd, c2s[a2]);
                if (s2 < s1 || (s2 == s1 && a2 < a1)) bk = a2;
            }
            sidxs[p] = bk;
            codes_f[base + p] = (float)bk;
        }
    }
    __syncthreads();

    // fallback: block-cooperative exact scan (executes ~never; must be exact)
    for (int fi = 0; fi < nfall; fi++) {
        int p = flist[fi];
        const float* rrow = resid + ((size_t)(base + p)) * Dd;
        float bv = INFINITY; int bk = 0;
        #pragma unroll
        for (int c = 0; c < 4; c++) {
            int k = tid * 4 + c;               // ascending within thread
            float sc = exact_score(rrow, cb + (size_t)k * Dd, c2s[k]);
            if (sc < bv || (sc == bv && k < bk)) { bv = sc; bk = k; }
        }
        #pragma unroll
        for (int off = 32; off; off >>= 1) {
            float v2 = __shfl_xor(bv, off);
            int   k2 = __shfl_xor(bk, off);
            if (v2 < bv || (v2 == bv && k2 < bk)) { bv = v2; bk = k2; }
        }
        if (ln == 0) { fwv[w] = bv; fwi[w] = bk; }
        __syncthreads();
        if (tid == 0) {
            float v = fwv[0]; int k = fwi[0];
            #pragma unroll
            for (int w2 = 1; w2 < 4; w2++) {
                if (fwv[w2] < v || (fwv[w2] == v && fwi[w2] < k)) {
                    v = fwv[w2]; k = fwi[w2];
                }
            }
            sidxs[p] = k;
            codes_f[base + p] = (float)k;
        }
        __syncthreads();
    }
    __syncthreads();

    // fused STE update: thread -> point tid>>2, dims [(tid&3)*32, +32)
    {
        int p = tid >> 2, dbeg = (tid & 3) * 32;
        float* rrow = resid + ((size_t)(base + p)) * Dd + dbeg;
        const float* qrow = cb + ((size_t)sidxs[p]) * Dd + dbeg;
        float cacc = 0.0f;
        #pragma unroll
        for (int hh = 0; hh < 8; hh++) {
            float4 r  = *(const float4*)(rrow + hh * 4);
            float4 qv = *(const float4*)(qrow + hh * 4);
            float t1x = qv.x - r.x, t1y = qv.y - r.y;
            float t1z = qv.z - r.z, t1w = qv.w - r.w;    // q - residual
            float qsx = r.x + t1x, qsy = r.y + t1y;
            float qsz = r.z + t1z, qsw = r.w + t1w;      // straight-through
            float4 nr = make_float4(r.x - qsx, r.y - qsy, r.z - qsz, r.w - qsw);
            *(float4*)(rrow + hh * 4) = nr;
            cacc = fmaf(t1x, t1x, cacc); cacc = fmaf(t1y, t1y, cacc);
            cacc = fmaf(t1z, t1z, cacc); cacc = fmaf(t1w, t1w, cacc);
        }
        #pragma unroll
        for (int off = 32; off; off >>= 1) cacc += __shfl_down(cacc, off);
        if (ln == 0) csum[w] = cacc;
    }
    __syncthreads();
    if (tid == 0)
        atomicAdd(commit, (double)(csum[0] + csum[1] + csum[2] + csum[3]));
}

// ---------------------------------------------------------------------------
// final: out(B,D,T) = x - resid_final^T
// ---------------------------------------------------------------------------
__global__ void k_final(const float* __restrict__ x,
                        const float* __restrict__ resid,
                        float* __restrict__ outq) {
    __shared__ float tile[32][33];
    int b  = blockIdx.z;
    int t0 = blockIdx.x * 32, d0 = blockIdx.y * 32;
    int tx = threadIdx.x, ty = threadIdx.y;   // 32 x 8
    #pragma unroll
    for (int k = 0; k < 4; k++) {
        int t = t0 + ty + k * 8;
        tile[ty + k * 8][tx] = resid[((size_t)(b * Tt + t)) * Dd + d0 + tx];
    }
    __syncthreads();
    #pragma unroll
    for (int k = 0; k < 4; k++) {
        int d = d0 + ty + k * 8;
        size_t o = ((size_t)(b * Dd + d)) * Tt + t0 + tx;
        outq[o] = x[o] - tile[tx][ty + k * 8];
    }
}

// ---------------------------------------------------------------------------
// scalars: bw = n_q * log2(K) * frame_rate ; penalty = mean(commits)
// ---------------------------------------------------------------------------
__global__ void k_scalars(const double* __restrict__ commits,
                          const int* __restrict__ frame_rate,
                          float* __restrict__ outs) {
    if (threadIdx.x == 0 && blockIdx.x == 0) {
        double s = 0.0;
        #pragma unroll
        for (int q = 0; q < NQ; q++) s += commits[q];
        double per_elem = s / ((double)NQ * (double)BT * (double)Dd);
        outs[0] = (float)(NQ * 10.0 * (double)frame_rate[0]); // log2(1024)=10
        outs[1] = (float)per_elem;
    }
}

extern "C" void kernel_launch(void* const* d_in, const int* in_sizes, int n_in,
                              void* d_out, int out_size, void* d_ws, size_t ws_size,
                              hipStream_t stream) {
    const float* x  = (const float*)d_in[0];   // (B, D, T)
    const float* cb = (const float*)d_in[1];   // (NQ, K, D)
    const int*   fr = (const int*)d_in[2];     // frame_rate

    float* outq    = (float*)d_out;                       // (B,D,T) 4194304
    float* codes_f = outq + (size_t)Bsz * Dd * Tt;        // (NQ,B,T) 262144
    float* scal    = codes_f + (size_t)NQ * BT;           // bw, penalty

    char* ws = (char*)d_ws;
    float*  resid   = (float*)ws;                              // BT*D f32
    float*  c2      = resid + (size_t)BT * Dd;                 // NQ*K f32
    double* commits = (double*)(c2 + (size_t)NQ * Kk);         // NQ f64
    char*   bswz    = (char*)(commits + NQ);                   // NQ*64*8192 B

    dim3 tb(32, 8, 1);
    k_init<<<dim3(Tt / 32, Dd / 32, Bsz), tb, 0, stream>>>(x, resid);
    k_prep<<<NQ * 256, 64, 0, stream>>>(cb, bswz);
    k_c2<<<NQ * Kk / 4, 256, 0, stream>>>(cb, c2, commits);

    for (int q = 0; q < NQ; q++) {
        k_argmin_mfma<<<BT / MT, 256, 0, stream>>>(
            resid,
            cb + (size_t)q * Kk * Dd,
            bswz + (size_t)q * 64 * 8192,
            c2 + (size_t)q * Kk,
            codes_f + (size_t)q * BT,
            commits + q);
    }

    k_final<<<dim3(Tt / 32, Dd / 32, Bsz), tb, 0, stream>>>(x, resid, outq);
    k_scalars<<<1, 64, 0, stream>>>(commits, fr, scal);
}